// Round 8
// baseline (105.380 us; speedup 1.0000x reference)
//
#include <hip/hip_runtime.h>

#define SEQd 64
#define BATCHd 256
#define DF 40

typedef float f2 __attribute__((ext_vector_type(2)));
typedef __fp16 h2v __attribute__((ext_vector_type(2)));

// ---------------------------------------------------------------------------
// 8-qubit statevector: 8 lanes/circuit, 32 amps (f2) per lane, 8 circuits/wave.
// Amp index p (8 bits, wire j <-> bit 7-j): lam = p & 7 (lane), k = p >> 3 (reg).
// Gate masks/sign-rows: the verified GF(2) schedule (unchanged constants).
// One wave per block, no __syncthreads anywhere: all LDS is wave-private,
// intra-wave LDS ordering is lgkmcnt-enforced by the compiler.
// ---------------------------------------------------------------------------

template<int LM>
__device__ __forceinline__ float xch1(float v) {
  if constexpr (LM == 0) {
    return v;
  } else if constexpr (LM == 1 || LM == 2 || LM == 3 || LM == 7) {
    constexpr int ctrl = (LM == 1) ? 0xB1 : (LM == 2) ? 0x4E : (LM == 3) ? 0x1B
                       : 0x141;   // 7 = row_half_mirror (xor7 within 8 lanes)
    return __int_as_float(__builtin_amdgcn_mov_dpp(__float_as_int(v), ctrl, 0xF, 0xF, true));
  } else {  // 4,5,6 -> ds_swizzle BitMode xor
    return __int_as_float(__builtin_amdgcn_ds_swizzle(__float_as_int(v), (LM << 10) | 0x1F));
  }
}

template<int LM>
__device__ __forceinline__ f2 xch2(f2 v) {
  if constexpr (LM == 0) return v;
  f2 r; r.x = xch1<LM>(v.x); r.y = xch1<LM>(v.y); return r;
}

__device__ __forceinline__ f2 ff(f2 x, f2 y, f2 z) { return __builtin_elementwise_fma(x, y, z); }
__device__ __forceinline__ f2 cmul(f2 a, f2 b) {
  f2 r; r.x = a.x * b.x - a.y * b.y; r.y = a.x * b.y + a.y * b.x; return r;
}
__device__ __forceinline__ f2 uget(float4 f, bool bit) {
  f2 r; r.x = bit ? f.z : f.x; r.y = bit ? -f.w : f.y; return r;
}

// RY: new = c*A + (parity(p&SM)? s : -s) * partner(p^M)
template<int M, int SM>
__device__ __forceinline__ void ry32(f2* a, f2 cs, int lam) {
  constexpr int LM = M & 7, RM = M >> 3, SL = SM & 7, SR = SM >> 3;
  float t0;
  if constexpr (SL != 0) t0 = (__popc(lam & SL) & 1) ? cs.y : -cs.y;
  else                   t0 = -cs.y;
  const f2 cv = {cs.x, cs.x};
  const f2 tp = {t0, t0}, tn = {-t0, -t0};
#pragma unroll
  for (int k = 0; k < 32; ++k) {
    const int kp = k ^ RM;
    if (kp < k) continue;
    if (kp == k) {
      const f2 b = xch2<LM>(a[k]);
      a[k] = ff(b, (__builtin_popcount(k & SR) & 1) ? tn : tp, a[k] * cv);
    } else {
      const f2 b0 = xch2<LM>(a[kp]);
      const f2 b1 = xch2<LM>(a[k]);
      const f2 t_k  = (__builtin_popcount(k  & SR) & 1) ? tn : tp;
      const f2 t_kp = (__builtin_popcount(kp & SR) & 1) ? tn : tp;
      a[k]  = ff(b0, t_k,  a[k]  * cv);
      a[kp] = ff(b1, t_kp, a[kp] * cv);
    }
  }
}

// Fused U = RY(ty)*RX(tx), q=(a,b,c2,d)=(cy*cx, sy*sx, sy*cx, cy*sx).
template<int M, int SM>
__device__ __forceinline__ void su2_32(f2* a, float4 q, int lam) {
  constexpr int LM = M & 7, RM = M >> 3, SL = SM & 7, SR = SM >> 3;
  float sb, sc;
  if constexpr (SL != 0) {
    const bool p = (__popc(lam & SL) & 1) != 0;
    sb = p ? -q.y : q.y; sc = p ? -q.z : q.z;
  } else { sb = q.y; sc = q.z; }
  const f2 vqa = {q.x, q.x};
  const f2 vqw = {q.w, -q.w};
  const f2 vfc0 = {-sc, -sc}, vfb0 = {-sb, sb};
  const f2 vfc1 = { sc,  sc}, vfb1 = { sb, -sb};
#pragma unroll
  for (int k = 0; k < 32; ++k) {
    const int kp = k ^ RM;
    if (kp < k) continue;
    if (kp == k) {
      const f2 B = xch2<LM>(a[k]);
      const bool pk = (__builtin_popcount(k & SR) & 1) != 0;
      const f2 A = a[k];
      f2 r = A * vqa;
      r = ff(B, pk ? vfc1 : vfc0, r);
      r = ff(A.yx, pk ? vfb1 : vfb0, r);
      r = ff(B.yx, vqw, r);
      a[k] = r;
    } else {
      const f2 B0 = xch2<LM>(a[kp]);
      const f2 B1 = xch2<LM>(a[k]);
      const bool pk0 = (__builtin_popcount(k  & SR) & 1) != 0;
      const bool pk1 = (__builtin_popcount(kp & SR) & 1) != 0;
      const f2 A0 = a[k], A1 = a[kp];
      f2 r0 = A0 * vqa;
      r0 = ff(B0, pk0 ? vfc1 : vfc0, r0);
      r0 = ff(A0.yx, pk0 ? vfb1 : vfb0, r0);
      r0 = ff(B0.yx, vqw, r0);
      a[k] = r0;
      f2 r1 = A1 * vqa;
      r1 = ff(B1, pk1 ? vfc1 : vfc0, r1);
      r1 = ff(A1.yx, pk1 ? vfb1 : vfb0, r1);
      r1 = ff(B1.yx, vqw, r1);
      a[kp] = r1;
    }
  }
}

// 3 x [ring CNOT (free GF(2) relabeling) + 8 RY]; same verified constants.
template<typename CPtr>
__device__ __forceinline__ void layers32(f2* a, CPtr L, int lam) {
  ry32<0xC0,0x7F>(a, L[0],  lam);
  ry32<0x60,0xC0>(a, L[1],  lam);
  ry32<0x30,0xE0>(a, L[2],  lam);
  ry32<0x18,0xF0>(a, L[3],  lam);
  ry32<0x0C,0xF8>(a, L[4],  lam);
  ry32<0x06,0xFC>(a, L[5],  lam);
  ry32<0x03,0xFE>(a, L[6],  lam);
  ry32<0xC1,0xFF>(a, L[7],  lam);
  ry32<0xA0,0xD5>(a, L[8],  lam);
  ry32<0x50,0xBF>(a, L[9],  lam);
  ry32<0x28,0x5F>(a, L[10], lam);
  ry32<0x14,0xAF>(a, L[11], lam);
  ry32<0x0A,0x57>(a, L[12], lam);
  ry32<0x05,0xAB>(a, L[13], lam);
  ry32<0xC2,0x55>(a, L[14], lam);
  ry32<0x61,0xAA>(a, L[15], lam);
  ry32<0xF0,0x4C>(a, L[16], lam);
  ry32<0x78,0x6A>(a, L[17], lam);
  ry32<0x3C,0x35>(a, L[18], lam);
  ry32<0x1E,0x9A>(a, L[19], lam);
  ry32<0x0F,0xCD>(a, L[20], lam);
  ry32<0xC7,0x66>(a, L[21], lam);
  ry32<0xA3,0x33>(a, L[22], lam);
  ry32<0x91,0x99>(a, L[23], lam);
}

// initial fused RX*RY on all 8 wires (variational halves; F0 = I)
template<typename FPtr>
__device__ __forceinline__ void initial32(f2* a, FPtr F, int lam) {
  su2_32<0x80,0x80>(a, F[0], lam);
  su2_32<0x40,0x40>(a, F[1], lam);
  su2_32<0x20,0x20>(a, F[2], lam);
  su2_32<0x10,0x10>(a, F[3], lam);
  su2_32<0x08,0x08>(a, F[4], lam);
  su2_32<0x04,0x04>(a, F[5], lam);
  su2_32<0x02,0x02>(a, F[6], lam);
  su2_32<0x01,0x01>(a, F[7], lam);
}

// Encoding half from |0..0>: product state, zero exchanges.
__device__ __forceinline__ void pinit32(f2* a, const float4* F, int lam) {
  f2 c = {1.f, 0.f};
#pragma unroll
  for (int i = 0; i < 3; ++i)
    c = cmul(c, uget(F[7 - i], ((lam >> i) & 1) != 0));
  f2 wlo[4], whi[8];
#pragma unroll
  for (int t = 0; t < 4; ++t)
    wlo[t] = cmul(uget(F[4], (t & 1) != 0), uget(F[3], ((t >> 1) & 1) != 0));
#pragma unroll
  for (int t = 0; t < 8; ++t)
    whi[t] = cmul(cmul(uget(F[2], (t & 1) != 0), uget(F[1], ((t >> 1) & 1) != 0)),
                  uget(F[0], ((t >> 2) & 1) != 0));
#pragma unroll
  for (int k = 0; k < 32; ++k)
    a[k] = cmul(cmul(c, wlo[k & 3]), whi[k >> 2]);
}

__device__ __forceinline__ uint32_t packh(f2 v) {
  h2v h = __builtin_amdgcn_cvt_pkrtz(v.x, v.y);
  return __builtin_bit_cast(uint32_t, h);
}
__device__ __forceinline__ f2 unpackh(uint32_t u) {
  h2v h = __builtin_bit_cast(h2v, u);
  f2 r; r.x = (float)h[0]; r.y = (float)h[1]; return r;
}

// snapshot: value at slot p stored at address F3*p (resets relabeling to I).
// Layout: word index = (q&7)*36 + (q>>3); per-lam stride 36, circuit stride 296.
__device__ __forceinline__ void snap_write32(const f2* a, uint32_t* sn, int lam) {
  int tgt = 0;                       // F3 columns for amp bits 0..2 (lane bits)
  if (lam & 1) tgt ^= 0x2B;
  if (lam & 2) tgt ^= 0x56;
  if (lam & 4) tgt ^= 0xAC;
#pragma unroll
  for (int k = 0; k < 32; ++k) {     // F3 columns for amp bits 3..7 (reg bits)
    const int rck = ((k & 1) ? 0xD9 : 0) ^ ((k & 2) ? 0x33 : 0) ^ ((k & 4) ? 0x66 : 0)
                  ^ ((k & 8) ? 0xCC : 0) ^ ((k & 16) ? 0x19 : 0);
    const int qq = tgt ^ rck;
    sn[(qq & 7) * 36 + (qq >> 3)] = packh(a[k]);
  }
}

__device__ __forceinline__ void snap_read32(f2* a, const uint32_t* sn, int lam) {
  const uint4* p = (const uint4*)(sn + lam * 36);
#pragma unroll
  for (int t = 0; t < 8; ++t) {
    const uint4 w = p[t];
    a[4*t+0] = unpackh(w.x); a[4*t+1] = unpackh(w.y);
    a[4*t+2] = unpackh(w.z); a[4*t+3] = unpackh(w.w);
  }
}

// <Z...>: Z0 -> SM 0x4C; Zall -> SM 0x88 (F3 rows; unchanged constants)
template<int SM>
__device__ __forceinline__ float expect32(const f2* a, int lam) {
  constexpr int SL = SM & 7, SR = SM >> 3;
  float s0 = 0.f, s1 = 0.f;
#pragma unroll
  for (int k = 0; k < 32; ++k) {
    const float p = a[k].x * a[k].x + a[k].y * a[k].y;
    if ((__builtin_popcount(k & SR) & 1) != 0) s1 += p; else s0 += p;
  }
  const float d = s0 - s1;
  float v;
  if constexpr (SL != 0) v = (__popc(lam & SL) & 1) ? -d : d;
  else                   v = d;
  v += xch1<1>(v); v += xch1<2>(v); v += xch1<4>(v);
  return v;
}

// per-(s,half) variational coefficient tables: 80 floats = 8*float4 + 24*float2
__global__ __launch_bounds__(256) void prep_var(
    const float* __restrict__ pQ, const float* __restrict__ pK,
    const float* __restrict__ pV, float* __restrict__ vtab)
{
  const int t = blockIdx.x * 256 + threadIdx.x;
  if (t >= SEQd * 3 * 32) return;
  const int slot = t & 31;
  const int sh = t >> 5;
  const int h = sh % 3, sp = sh / 3;
  const float* w = ((h == 0) ? pQ : (h == 1) ? pK : pV) + sp * DF;
  float* o = vtab + sh * 80;
  if (slot < 8) {
    float cx, sx, cy, sy;
    __sincosf(w[2 * slot]     * 0.5f, &sx, &cx);
    __sincosf(w[2 * slot + 1] * 0.5f, &sy, &cy);
    ((float4*)o)[slot] = make_float4(cy * cx, sy * sx, sy * cx, cy * sx);
  } else {
    float sn, cn;
    __sincosf(w[16 + (slot - 8)] * 0.5f, &sn, &cn);
    ((float2*)(o + 32))[slot - 8] = make_float2(cn, sn);
  }
}

// One wave per block; 8 circuits per wave (all same s). No barriers anywhere:
// etab/snap are wave-private, lgkmcnt ordering suffices. Var coefs are wave-
// uniform -> scalar loads from global (offset pinned via readfirstlane).
__global__ __launch_bounds__(64, 4) void qsal_circuits(
    const float* __restrict__ x, const float* __restrict__ vtab,
    float* __restrict__ Qo, float* __restrict__ Ko, float* __restrict__ Vo)
{
  __shared__ __align__(16) float etab[8][84];
  __shared__ __align__(16) uint32_t snap[8][296];
  const int tid = threadIdx.x;             // 0..63 (one wave)
  const int lam = tid & 7;
  const int cig = tid >> 3;                // circuit index 0..7
  const int s = blockIdx.x & 63;
  const int bbase = (blockIdx.x >> 6) << 3;

  // fill enc coef tables: 8 circuits x 40 angles (5 iters/lane)
  for (int t = tid; t < 320; t += 64) {
    const int cc = t / 40, idx = t - cc * 40;
    const float ang = x[((size_t)(bbase + cc) * 64 + s) * 40 + idx];
    float sn, cn; __sincosf(ang * 0.5f, &sn, &cn);
    if (idx < 16) {
      const int wire = idx >> 1, isy = idx & 1;
      etab[cc][wire * 4 + isy * 2 + 0] = cn;
      etab[cc][wire * 4 + isy * 2 + 1] = sn;
    } else {
      etab[cc][32 + (idx - 16) * 2 + 0] = cn;
      etab[cc][32 + (idx - 16) * 2 + 1] = sn;
    }
  }
  {  // fold enc (cx,sx,cy,sy) -> (a,b,c2,d): 8 circuits x 8 wires = 64 lanes
    const int cc = tid >> 3, wire = tid & 7;
    float4* qt = (float4*)etab[cc];
    const float4 f = qt[wire];
    qt[wire] = make_float4(f.z * f.x, f.w * f.y, f.w * f.x, f.z * f.y);
  }

  f2 st[32];
  // encoding half (LDS coef instance)
  pinit32(st, (const float4*)etab[cig], lam);
  layers32(st, (const f2*)(etab[cig] + 32), lam);
  snap_write32(st, snap[cig], lam);

  // 3 variational halves (global scalar coef instance)
#pragma unroll 1
  for (int h = 0; h < 3; ++h) {
    const int voff = __builtin_amdgcn_readfirstlane(s * 240 + h * 80);
    const float* th = vtab + voff;
    snap_read32(st, snap[cig], lam);
    initial32(st, (const float4*)th, lam);
    layers32(st, (const f2*)(th + 32), lam);
    const float e = (h == 2) ? expect32<0x88>(st, lam) : expect32<0x4C>(st, lam);
    if (lam == 0) {
      float* op = (h == 0) ? Qo : (h == 1) ? Ko : Vo;
      op[(bbase + cig) * 64 + s] = e;
    }
  }
}

__global__ __launch_bounds__(256) void qsal_attn(
    const float* __restrict__ x,
    const float* __restrict__ Qv,
    const float* __restrict__ Kv,
    const float* __restrict__ Vv,
    float* __restrict__ out)
{
  const int tid  = threadIdx.x;
  const int wid  = tid >> 6;
  const int lane = tid & 63;                 // m
  const int bi   = blockIdx.x * 4 + wid;     // b*64 + i
  const int b    = bi >> 6;

  const float q = Qv[bi];
  const float k = Kv[b * 64 + lane];
  const float v = Vv[b * 64 + lane];
  const float d = q - k;
  float e  = __expf(-d * d);
  float ev = e * v;
#pragma unroll
  for (int m = 1; m < 64; m <<= 1) {
    e  += __shfl_xor(e,  m, 64);
    ev += __shfl_xor(ev, m, 64);
  }
  const float att = ev / e;

  const size_t row = (size_t)bi * DF;
  if (lane < DF) out[row + lane] = x[row + lane] + att;
}

extern "C" void kernel_launch(void* const* d_in, const int* in_sizes, int n_in,
                              void* d_out, int out_size, void* d_ws, size_t ws_size,
                              hipStream_t stream) {
  const float* x  = (const float*)d_in[0];
  const float* pQ = (const float*)d_in[1];
  const float* pK = (const float*)d_in[2];
  const float* pV = (const float*)d_in[3];
  float* out = (float*)d_out;

  float* Qv   = (float*)d_ws;                    // [16384]
  float* Kv   = Qv + BATCHd * SEQd;
  float* Vv   = Kv + BATCHd * SEQd;
  float* vtab = Vv + BATCHd * SEQd;              // [64*3*80]

  prep_var<<<dim3(24), dim3(256), 0, stream>>>(pQ, pK, pV, vtab);
  qsal_circuits<<<dim3(2048), dim3(64), 0, stream>>>(x, vtab, Qv, Kv, Vv);
  qsal_attn<<<dim3(BATCHd * SEQd / 4), dim3(256), 0, stream>>>(x, Qv, Kv, Vv, out);
}

// Round 9
// 87.782 us; speedup vs baseline: 1.2005x; 1.2005x over previous
//
#include <hip/hip_runtime.h>

#define SEQd 64
#define BATCHd 256
#define DF 40

typedef float f2 __attribute__((ext_vector_type(2)));
typedef __fp16 h2v __attribute__((ext_vector_type(2)));

// ---------------------------------------------------------------------------
// 8-qubit statevector: 8 lanes/circuit, 32 amps (f2) per lane, 8 circuits/wave.
// Amp index p (8 bits, wire j <-> bit 7-j): lam = p & 7 (lane), k = p >> 3 (reg).
// Gate masks/sign-rows: the verified GF(2) schedule (unchanged constants).
// ---------------------------------------------------------------------------

template<int LM>
__device__ __forceinline__ float xch1(float v) {
  if constexpr (LM == 0) {
    return v;
  } else if constexpr (LM == 1 || LM == 2 || LM == 3 || LM == 7) {
    constexpr int ctrl = (LM == 1) ? 0xB1 : (LM == 2) ? 0x4E : (LM == 3) ? 0x1B
                       : 0x141;   // 7 = row_half_mirror (xor7 within 8 lanes)
    return __int_as_float(__builtin_amdgcn_mov_dpp(__float_as_int(v), ctrl, 0xF, 0xF, true));
  } else {  // 4,5,6 -> ds_swizzle BitMode xor
    return __int_as_float(__builtin_amdgcn_ds_swizzle(__float_as_int(v), (LM << 10) | 0x1F));
  }
}

template<int LM>
__device__ __forceinline__ f2 xch2(f2 v) {
  if constexpr (LM == 0) return v;
  f2 r; r.x = xch1<LM>(v.x); r.y = xch1<LM>(v.y); return r;
}

__device__ __forceinline__ f2 ff(f2 x, f2 y, f2 z) { return __builtin_elementwise_fma(x, y, z); }
__device__ __forceinline__ f2 cmul(f2 a, f2 b) {
  f2 r; r.x = a.x * b.x - a.y * b.y; r.y = a.x * b.y + a.y * b.x; return r;
}
__device__ __forceinline__ f2 uget(float4 f, bool bit) {
  f2 r; r.x = bit ? f.z : f.x; r.y = bit ? -f.w : f.y; return r;
}

// RY: new = c*A + (parity(p&SM)? s : -s) * partner(p^M)
template<int M, int SM>
__device__ __forceinline__ void ry32(f2* a, f2 cs, int lam) {
  constexpr int LM = M & 7, RM = M >> 3, SL = SM & 7, SR = SM >> 3;
  float t0;
  if constexpr (SL != 0) t0 = (__popc(lam & SL) & 1) ? cs.y : -cs.y;
  else                   t0 = -cs.y;
  const f2 cv = {cs.x, cs.x};
  const f2 tp = {t0, t0}, tn = {-t0, -t0};
#pragma unroll
  for (int k = 0; k < 32; ++k) {
    const int kp = k ^ RM;
    if (kp < k) continue;
    if (kp == k) {
      const f2 b = xch2<LM>(a[k]);
      a[k] = ff(b, (__builtin_popcount(k & SR) & 1) ? tn : tp, a[k] * cv);
    } else {
      const f2 b0 = xch2<LM>(a[kp]);
      const f2 b1 = xch2<LM>(a[k]);
      const f2 t_k  = (__builtin_popcount(k  & SR) & 1) ? tn : tp;
      const f2 t_kp = (__builtin_popcount(kp & SR) & 1) ? tn : tp;
      a[k]  = ff(b0, t_k,  a[k]  * cv);
      a[kp] = ff(b1, t_kp, a[kp] * cv);
    }
  }
}

// Fused U = RY(ty)*RX(tx), q=(a,b,c2,d)=(cy*cx, sy*sx, sy*cx, cy*sx).
template<int M, int SM>
__device__ __forceinline__ void su2_32(f2* a, float4 q, int lam) {
  constexpr int LM = M & 7, RM = M >> 3, SL = SM & 7, SR = SM >> 3;
  float sb, sc;
  if constexpr (SL != 0) {
    const bool p = (__popc(lam & SL) & 1) != 0;
    sb = p ? -q.y : q.y; sc = p ? -q.z : q.z;
  } else { sb = q.y; sc = q.z; }
  const f2 vqa = {q.x, q.x};
  const f2 vqw = {q.w, -q.w};
  const f2 vfc0 = {-sc, -sc}, vfb0 = {-sb, sb};
  const f2 vfc1 = { sc,  sc}, vfb1 = { sb, -sb};
#pragma unroll
  for (int k = 0; k < 32; ++k) {
    const int kp = k ^ RM;
    if (kp < k) continue;
    if (kp == k) {
      const f2 B = xch2<LM>(a[k]);
      const bool pk = (__builtin_popcount(k & SR) & 1) != 0;
      const f2 A = a[k];
      f2 r = A * vqa;
      r = ff(B, pk ? vfc1 : vfc0, r);
      r = ff(A.yx, pk ? vfb1 : vfb0, r);
      r = ff(B.yx, vqw, r);
      a[k] = r;
    } else {
      const f2 B0 = xch2<LM>(a[kp]);
      const f2 B1 = xch2<LM>(a[k]);
      const bool pk0 = (__builtin_popcount(k  & SR) & 1) != 0;
      const bool pk1 = (__builtin_popcount(kp & SR) & 1) != 0;
      const f2 A0 = a[k], A1 = a[kp];
      f2 r0 = A0 * vqa;
      r0 = ff(B0, pk0 ? vfc1 : vfc0, r0);
      r0 = ff(A0.yx, pk0 ? vfb1 : vfb0, r0);
      r0 = ff(B0.yx, vqw, r0);
      a[k] = r0;
      f2 r1 = A1 * vqa;
      r1 = ff(B1, pk1 ? vfc1 : vfc0, r1);
      r1 = ff(A1.yx, pk1 ? vfb1 : vfb0, r1);
      r1 = ff(B1.yx, vqw, r1);
      a[kp] = r1;
    }
  }
}

// 3 x [ring CNOT (free GF(2) relabeling) + 8 RY]; same verified constants.
template<typename CPtr>
__device__ __forceinline__ void layers32(f2* a, CPtr L, int lam) {
  ry32<0xC0,0x7F>(a, L[0],  lam);
  ry32<0x60,0xC0>(a, L[1],  lam);
  ry32<0x30,0xE0>(a, L[2],  lam);
  ry32<0x18,0xF0>(a, L[3],  lam);
  ry32<0x0C,0xF8>(a, L[4],  lam);
  ry32<0x06,0xFC>(a, L[5],  lam);
  ry32<0x03,0xFE>(a, L[6],  lam);
  ry32<0xC1,0xFF>(a, L[7],  lam);
  ry32<0xA0,0xD5>(a, L[8],  lam);
  ry32<0x50,0xBF>(a, L[9],  lam);
  ry32<0x28,0x5F>(a, L[10], lam);
  ry32<0x14,0xAF>(a, L[11], lam);
  ry32<0x0A,0x57>(a, L[12], lam);
  ry32<0x05,0xAB>(a, L[13], lam);
  ry32<0xC2,0x55>(a, L[14], lam);
  ry32<0x61,0xAA>(a, L[15], lam);
  ry32<0xF0,0x4C>(a, L[16], lam);
  ry32<0x78,0x6A>(a, L[17], lam);
  ry32<0x3C,0x35>(a, L[18], lam);
  ry32<0x1E,0x9A>(a, L[19], lam);
  ry32<0x0F,0xCD>(a, L[20], lam);
  ry32<0xC7,0x66>(a, L[21], lam);
  ry32<0xA3,0x33>(a, L[22], lam);
  ry32<0x91,0x99>(a, L[23], lam);
}

// initial fused RX*RY on all 8 wires (variational halves; F0 = I)
template<typename FPtr>
__device__ __forceinline__ void initial32(f2* a, FPtr F, int lam) {
  su2_32<0x80,0x80>(a, F[0], lam);
  su2_32<0x40,0x40>(a, F[1], lam);
  su2_32<0x20,0x20>(a, F[2], lam);
  su2_32<0x10,0x10>(a, F[3], lam);
  su2_32<0x08,0x08>(a, F[4], lam);
  su2_32<0x04,0x04>(a, F[5], lam);
  su2_32<0x02,0x02>(a, F[6], lam);
  su2_32<0x01,0x01>(a, F[7], lam);
}

// Encoding half from |0..0>: product state, zero exchanges.
__device__ __forceinline__ void pinit32(f2* a, const float4* F, int lam) {
  f2 c = {1.f, 0.f};
#pragma unroll
  for (int i = 0; i < 3; ++i)
    c = cmul(c, uget(F[7 - i], ((lam >> i) & 1) != 0));
  f2 wlo[4], whi[8];
#pragma unroll
  for (int t = 0; t < 4; ++t)
    wlo[t] = cmul(uget(F[4], (t & 1) != 0), uget(F[3], ((t >> 1) & 1) != 0));
#pragma unroll
  for (int t = 0; t < 8; ++t)
    whi[t] = cmul(cmul(uget(F[2], (t & 1) != 0), uget(F[1], ((t >> 1) & 1) != 0)),
                  uget(F[0], ((t >> 2) & 1) != 0));
#pragma unroll
  for (int k = 0; k < 32; ++k)
    a[k] = cmul(cmul(c, wlo[k & 3]), whi[k >> 2]);
}

__device__ __forceinline__ uint32_t packh(f2 v) {
  h2v h = __builtin_amdgcn_cvt_pkrtz(v.x, v.y);
  return __builtin_bit_cast(uint32_t, h);
}
__device__ __forceinline__ f2 unpackh(uint32_t u) {
  h2v h = __builtin_bit_cast(h2v, u);
  f2 r; r.x = (float)h[0]; r.y = (float)h[1]; return r;
}

// F3 target address for the snapshot relabel reset (value at slot p -> F3*p)
__device__ __forceinline__ int snap_tgt_lane(int lam) {
  int tgt = 0;
  if (lam & 1) tgt ^= 0x2B;
  if (lam & 2) tgt ^= 0x56;
  if (lam & 4) tgt ^= 0xAC;
  return tgt;
}
__device__ __forceinline__ int snap_rck(int k) {
  return ((k & 1) ? 0xD9 : 0) ^ ((k & 2) ? 0x33 : 0) ^ ((k & 4) ? 0x66 : 0)
       ^ ((k & 8) ? 0xCC : 0) ^ ((k & 16) ? 0x19 : 0);
}

// split-path snapshot: per-circuit 256 words, word = (q&7)*32 + (q>>3)
__device__ __forceinline__ void snap_write_g(const f2* a, uint32_t* sn, int lam) {
  const int tgt = snap_tgt_lane(lam);
#pragma unroll
  for (int k = 0; k < 32; ++k) {
    const int qq = tgt ^ snap_rck(k);
    sn[(qq & 7) * 32 + (qq >> 3)] = packh(a[k]);
  }
}

// mono-path snapshot (stride 36, as in the proven 77us kernel)
__device__ __forceinline__ void snap_write_m(const f2* a, uint32_t* sn, int lam) {
  const int tgt = snap_tgt_lane(lam);
#pragma unroll
  for (int k = 0; k < 32; ++k) {
    const int qq = tgt ^ snap_rck(k);
    sn[(qq & 7) * 36 + (qq >> 3)] = packh(a[k]);
  }
}
__device__ __forceinline__ void snap_read_m(f2* a, const uint32_t* sn, int lam) {
  const uint4* p = (const uint4*)(sn + lam * 36);
#pragma unroll
  for (int t = 0; t < 8; ++t) {
    const uint4 w = p[t];
    a[4*t+0] = unpackh(w.x); a[4*t+1] = unpackh(w.y);
    a[4*t+2] = unpackh(w.z); a[4*t+3] = unpackh(w.w);
  }
}

// <Z...>: Z0 -> SM 0x4C; Zall -> SM 0x88 (F3 rows; unchanged constants)
template<int SM>
__device__ __forceinline__ float expect32(const f2* a, int lam) {
  constexpr int SL = SM & 7, SR = SM >> 3;
  float s0 = 0.f, s1 = 0.f;
#pragma unroll
  for (int k = 0; k < 32; ++k) {
    const float p = a[k].x * a[k].x + a[k].y * a[k].y;
    if ((__builtin_popcount(k & SR) & 1) != 0) s1 += p; else s0 += p;
  }
  const float d = s0 - s1;
  float v;
  if constexpr (SL != 0) v = (__popc(lam & SL) & 1) ? -d : d;
  else                   v = d;
  v += xch1<1>(v); v += xch1<2>(v); v += xch1<4>(v);
  return v;
}

// fill one wave's 8 enc coef tables (wave-private; lgkmcnt orders LDS ops)
__device__ __forceinline__ void fill_etab(float (*et)[84], const float* __restrict__ x,
                                          int bbase, int s, int lane) {
  for (int t = lane; t < 320; t += 64) {
    const int cc = t / 40, idx = t - cc * 40;
    const float ang = x[((size_t)(bbase + cc) * 64 + s) * 40 + idx];
    float sn, cn; __sincosf(ang * 0.5f, &sn, &cn);
    if (idx < 16) {
      const int wire = idx >> 1, isy = idx & 1;
      et[cc][wire * 4 + isy * 2 + 0] = cn;
      et[cc][wire * 4 + isy * 2 + 1] = sn;
    } else {
      et[cc][32 + (idx - 16) * 2 + 0] = cn;
      et[cc][32 + (idx - 16) * 2 + 1] = sn;
    }
  }
  {  // fold (cx,sx,cy,sy) -> (a,b,c2,d): 8 circuits x 8 wires = 64 lanes
    const int cc = lane >> 3, wire = lane & 7;
    float4* qt = (float4*)et[cc];
    const float4 f = qt[wire];
    qt[wire] = make_float4(f.z * f.x, f.w * f.y, f.w * f.x, f.z * f.y);
  }
}

// per-(s,half) variational coefficient tables: 80 floats = 8*float4 + 24*float2
__global__ __launch_bounds__(256) void prep_var(
    const float* __restrict__ pQ, const float* __restrict__ pK,
    const float* __restrict__ pV, float* __restrict__ vtab)
{
  const int t = blockIdx.x * 256 + threadIdx.x;
  if (t >= SEQd * 3 * 32) return;
  const int slot = t & 31;
  const int sh = t >> 5;
  const int h = sh % 3, sp = sh / 3;
  const float* w = ((h == 0) ? pQ : (h == 1) ? pK : pV) + sp * DF;
  float* o = vtab + sh * 80;
  if (slot < 8) {
    float cx, sx, cy, sy;
    __sincosf(w[2 * slot]     * 0.5f, &sx, &cx);
    __sincosf(w[2 * slot + 1] * 0.5f, &sy, &cy);
    ((float4*)o)[slot] = make_float4(cy * cx, sy * sx, sy * cx, cy * sx);
  } else {
    float sn, cn;
    __sincosf(w[16 + (slot - 8)] * 0.5f, &sn, &cn);
    ((float2*)(o + 32))[slot - 8] = make_float2(cn, sn);
  }
}

// === Kernel A: encoding halves -> fp16 snapshot in global (coalesced) ======
__global__ __launch_bounds__(256) void qsal_enc(
    const float* __restrict__ x, uint32_t* __restrict__ snapg)
{
  __shared__ __align__(16) float etab[4][8][84];
  __shared__ __align__(16) uint32_t snap[4][8][264];
  const int tid = threadIdx.x;
  const int wid = tid >> 6, lane = tid & 63;
  const int lam = lane & 7, cig = lane >> 3;
  const int cgrp = blockIdx.x * 4 + wid;
  const int s = cgrp & 63;
  const int bbase = (cgrp >> 6) << 3;

  fill_etab(etab[wid], x, bbase, s, lane);

  f2 st[32];
  pinit32(st, (const float4*)etab[wid][cig], lam);
  layers32(st, (const f2*)(etab[wid][cig] + 32), lam);
  snap_write_g(st, snap[wid][cig], lam);

  // LDS -> global, coalesced: each circuit's 256 words are q-linear
  uint32_t* gb = snapg + ((size_t)cgrp * 8 + cig) * 256;
#pragma unroll
  for (int r = 0; r < 8; ++r) {
    const int u4 = lam + 8 * r;                       // uint4 idx 0..63
    const uint4 v = *(const uint4*)&snap[wid][cig][u4 * 4];
    ((uint4*)gb)[u4] = v;
  }
}

// === Kernel B: one variational half per wave (3 waves/block, no barriers) ==
__global__ __launch_bounds__(192) void qsal_var(
    const uint32_t* __restrict__ snapg, const float* __restrict__ vtab,
    float* __restrict__ Qo, float* __restrict__ Ko, float* __restrict__ Vo)
{
  __shared__ __align__(16) float ltab[3][80];
  const int tid = threadIdx.x;
  const int h = tid / 64, lane = tid & 63;           // h = wave id = half
  const int lam = lane & 7, cig = lane >> 3;
  const int cgrp = blockIdx.x;
  const int s = cgrp & 63;
  const int bbase = (cgrp >> 6) << 3;

  if (lane < 20)
    ((float4*)ltab[h])[lane] = ((const float4*)(vtab + s * 240 + h * 80))[lane];

  f2 st[32];
  const uint4* sp = (const uint4*)(snapg + (((size_t)cgrp * 8 + cig) * 256 + lam * 32));
#pragma unroll
  for (int t = 0; t < 8; ++t) {
    const uint4 w = sp[t];
    st[4*t+0] = unpackh(w.x); st[4*t+1] = unpackh(w.y);
    st[4*t+2] = unpackh(w.z); st[4*t+3] = unpackh(w.w);
  }
  initial32(st, (const float4*)ltab[h], lam);
  layers32(st, (const f2*)(ltab[h] + 32), lam);
  const float e = (h == 2) ? expect32<0x88>(st, lam) : expect32<0x4C>(st, lam);
  if (lam == 0) {
    float* op = (h == 0) ? Qo : (h == 1) ? Ko : Vo;
    op[(bbase + cig) * 64 + s] = e;
  }
}

// === Fallback: the proven 77us monolithic kernel (ws too small for split) ==
__global__ __launch_bounds__(256, 3) void qsal_mono(
    const float* __restrict__ x, const float* __restrict__ vtab,
    float* __restrict__ Qo, float* __restrict__ Ko, float* __restrict__ Vo)
{
  __shared__ __align__(16) float etab[32][84];
  __shared__ __align__(16) uint32_t snap[32][296];
  __shared__ __align__(16) float vtabs[240];
  const int tid = threadIdx.x;
  const int wid = tid >> 6, lane = tid & 63;
  const int lam = lane & 7;
  const int cig = (wid << 3) | (lane >> 3);
  const int s = blockIdx.x & 63;
  const int bbase = (blockIdx.x >> 6) << 5;

  for (int t = tid; t < 1280; t += 256) {
    const int cc = t / 40, idx = t - cc * 40;
    const float ang = x[((size_t)(bbase + cc) * 64 + s) * 40 + idx];
    float sn, cn; __sincosf(ang * 0.5f, &sn, &cn);
    if (idx < 16) {
      const int wire = idx >> 1, isy = idx & 1;
      etab[cc][wire * 4 + isy * 2 + 0] = cn;
      etab[cc][wire * 4 + isy * 2 + 1] = sn;
    } else {
      etab[cc][32 + (idx - 16) * 2 + 0] = cn;
      etab[cc][32 + (idx - 16) * 2 + 1] = sn;
    }
  }
  if (tid < 60) ((float4*)vtabs)[tid] = ((const float4*)(vtab + s * 240))[tid];
  __syncthreads();
  {
    const int cc = tid >> 3, wire = tid & 7;
    float4* qt = (float4*)etab[cc];
    const float4 f = qt[wire];
    qt[wire] = make_float4(f.z * f.x, f.w * f.y, f.w * f.x, f.z * f.y);
  }
  __syncthreads();

  f2 st[32];
#pragma unroll 1
  for (int ph = 0; ph < 4; ++ph) {
    const f2* L;
    if (ph == 0) {
      pinit32(st, (const float4*)etab[cig], lam);
      L = (const f2*)(etab[cig] + 32);
    } else {
      snap_read_m(st, snap[cig], lam);
      const float* th = vtabs + (ph - 1) * 80;
      initial32(st, (const float4*)th, lam);
      L = (const f2*)(th + 32);
    }
    layers32(st, L, lam);
    if (ph == 0) {
      snap_write_m(st, snap[cig], lam);
    } else {
      const float e = (ph == 3) ? expect32<0x88>(st, lam) : expect32<0x4C>(st, lam);
      if (lam == 0) {
        float* op = (ph == 1) ? Qo : (ph == 2) ? Ko : Vo;
        op[(bbase + cig) * 64 + s] = e;
      }
    }
    __syncthreads();
  }
}

__global__ __launch_bounds__(256) void qsal_attn(
    const float* __restrict__ x,
    const float* __restrict__ Qv,
    const float* __restrict__ Kv,
    const float* __restrict__ Vv,
    float* __restrict__ out)
{
  const int tid  = threadIdx.x;
  const int wid  = tid >> 6;
  const int lane = tid & 63;                 // m
  const int bi   = blockIdx.x * 4 + wid;     // b*64 + i
  const int b    = bi >> 6;

  const float q = Qv[bi];
  const float k = Kv[b * 64 + lane];
  const float v = Vv[b * 64 + lane];
  const float d = q - k;
  float e  = __expf(-d * d);
  float ev = e * v;
#pragma unroll
  for (int m = 1; m < 64; m <<= 1) {
    e  += __shfl_xor(e,  m, 64);
    ev += __shfl_xor(ev, m, 64);
  }
  const float att = ev / e;

  const size_t row = (size_t)bi * DF;
  if (lane < DF) out[row + lane] = x[row + lane] + att;
}

extern "C" void kernel_launch(void* const* d_in, const int* in_sizes, int n_in,
                              void* d_out, int out_size, void* d_ws, size_t ws_size,
                              hipStream_t stream) {
  const float* x  = (const float*)d_in[0];
  const float* pQ = (const float*)d_in[1];
  const float* pK = (const float*)d_in[2];
  const float* pV = (const float*)d_in[3];
  float* out = (float*)d_out;

  const int NC = BATCHd * SEQd;                  // 16384 circuits
  float* Qv   = (float*)d_ws;                    // [16384]
  float* Kv   = Qv + NC;
  float* Vv   = Kv + NC;
  float* vtab = Vv + NC;                         // [64*3*80] = 15360
  uint32_t* snapg = (uint32_t*)(vtab + SEQd * 3 * 80);   // [16384*256] u32 = 16 MB

  const size_t need = (size_t)(3 * NC + SEQd * 3 * 80) * 4 + (size_t)NC * 256 * 4;

  prep_var<<<dim3(24), dim3(256), 0, stream>>>(pQ, pK, pV, vtab);
  if (ws_size >= need) {
    qsal_enc<<<dim3(512), dim3(256), 0, stream>>>(x, snapg);
    qsal_var<<<dim3(2048), dim3(192), 0, stream>>>(snapg, vtab, Qv, Kv, Vv);
  } else {
    qsal_mono<<<dim3(512), dim3(256), 0, stream>>>(x, vtab, Qv, Kv, Vv);
  }
  qsal_attn<<<dim3(NC / 4), dim3(256), 0, stream>>>(x, Qv, Kv, Vv, out);
}

// Round 10
// 87.722 us; speedup vs baseline: 1.2013x; 1.0007x over previous
//
#include <hip/hip_runtime.h>

#define SEQd 64
#define BATCHd 256
#define DF 40

typedef float f2 __attribute__((ext_vector_type(2)));
typedef __fp16 h2v __attribute__((ext_vector_type(2)));

// ---------------------------------------------------------------------------
// 8-qubit statevector: 8 lanes/circuit, 32 amps (f2) per lane, 8 circuits/wave.
// Amp index p (8 bits, wire j <-> bit 7-j): lam = p & 7 (lane), k = p >> 3 (reg).
// Gate masks/sign-rows: the verified GF(2) schedule (unchanged constants).
// NOTE on launch bounds: the st[32] state = 64 VGPRs; any bound that lets the
// allocator target >4 waves/SIMD spills it (R8: 64 VGPR, R9 var: 60 VGPR).
// Min-waves=3 (cap ~170) is the proven no-spill setting (R7: 84 VGPR).
// ---------------------------------------------------------------------------

template<int LM>
__device__ __forceinline__ float xch1(float v) {
  if constexpr (LM == 0) {
    return v;
  } else if constexpr (LM == 1 || LM == 2 || LM == 3 || LM == 7) {
    constexpr int ctrl = (LM == 1) ? 0xB1 : (LM == 2) ? 0x4E : (LM == 3) ? 0x1B
                       : 0x141;   // 7 = row_half_mirror (xor7 within 8 lanes)
    return __int_as_float(__builtin_amdgcn_mov_dpp(__float_as_int(v), ctrl, 0xF, 0xF, true));
  } else {  // 4,5,6 -> ds_swizzle BitMode xor
    return __int_as_float(__builtin_amdgcn_ds_swizzle(__float_as_int(v), (LM << 10) | 0x1F));
  }
}

template<int LM>
__device__ __forceinline__ f2 xch2(f2 v) {
  if constexpr (LM == 0) return v;
  f2 r; r.x = xch1<LM>(v.x); r.y = xch1<LM>(v.y); return r;
}

__device__ __forceinline__ f2 ff(f2 x, f2 y, f2 z) { return __builtin_elementwise_fma(x, y, z); }
__device__ __forceinline__ f2 cmul(f2 a, f2 b) {
  f2 r; r.x = a.x * b.x - a.y * b.y; r.y = a.x * b.y + a.y * b.x; return r;
}
__device__ __forceinline__ f2 uget(float4 f, bool bit) {
  f2 r; r.x = bit ? f.z : f.x; r.y = bit ? -f.w : f.y; return r;
}

// RY: new = c*A + (parity(p&SM)? s : -s) * partner(p^M)
template<int M, int SM>
__device__ __forceinline__ void ry32(f2* a, f2 cs, int lam) {
  constexpr int LM = M & 7, RM = M >> 3, SL = SM & 7, SR = SM >> 3;
  float t0;
  if constexpr (SL != 0) t0 = (__popc(lam & SL) & 1) ? cs.y : -cs.y;
  else                   t0 = -cs.y;
  const f2 cv = {cs.x, cs.x};
  const f2 tp = {t0, t0}, tn = {-t0, -t0};
#pragma unroll
  for (int k = 0; k < 32; ++k) {
    const int kp = k ^ RM;
    if (kp < k) continue;
    if (kp == k) {
      const f2 b = xch2<LM>(a[k]);
      a[k] = ff(b, (__builtin_popcount(k & SR) & 1) ? tn : tp, a[k] * cv);
    } else {
      const f2 b0 = xch2<LM>(a[kp]);
      const f2 b1 = xch2<LM>(a[k]);
      const f2 t_k  = (__builtin_popcount(k  & SR) & 1) ? tn : tp;
      const f2 t_kp = (__builtin_popcount(kp & SR) & 1) ? tn : tp;
      a[k]  = ff(b0, t_k,  a[k]  * cv);
      a[kp] = ff(b1, t_kp, a[kp] * cv);
    }
  }
}

// Fused U = RY(ty)*RX(tx), q=(a,b,c2,d)=(cy*cx, sy*sx, sy*cx, cy*sx).
template<int M, int SM>
__device__ __forceinline__ void su2_32(f2* a, float4 q, int lam) {
  constexpr int LM = M & 7, RM = M >> 3, SL = SM & 7, SR = SM >> 3;
  float sb, sc;
  if constexpr (SL != 0) {
    const bool p = (__popc(lam & SL) & 1) != 0;
    sb = p ? -q.y : q.y; sc = p ? -q.z : q.z;
  } else { sb = q.y; sc = q.z; }
  const f2 vqa = {q.x, q.x};
  const f2 vqw = {q.w, -q.w};
  const f2 vfc0 = {-sc, -sc}, vfb0 = {-sb, sb};
  const f2 vfc1 = { sc,  sc}, vfb1 = { sb, -sb};
#pragma unroll
  for (int k = 0; k < 32; ++k) {
    const int kp = k ^ RM;
    if (kp < k) continue;
    if (kp == k) {
      const f2 B = xch2<LM>(a[k]);
      const bool pk = (__builtin_popcount(k & SR) & 1) != 0;
      const f2 A = a[k];
      f2 r = A * vqa;
      r = ff(B, pk ? vfc1 : vfc0, r);
      r = ff(A.yx, pk ? vfb1 : vfb0, r);
      r = ff(B.yx, vqw, r);
      a[k] = r;
    } else {
      const f2 B0 = xch2<LM>(a[kp]);
      const f2 B1 = xch2<LM>(a[k]);
      const bool pk0 = (__builtin_popcount(k  & SR) & 1) != 0;
      const bool pk1 = (__builtin_popcount(kp & SR) & 1) != 0;
      const f2 A0 = a[k], A1 = a[kp];
      f2 r0 = A0 * vqa;
      r0 = ff(B0, pk0 ? vfc1 : vfc0, r0);
      r0 = ff(A0.yx, pk0 ? vfb1 : vfb0, r0);
      r0 = ff(B0.yx, vqw, r0);
      a[k] = r0;
      f2 r1 = A1 * vqa;
      r1 = ff(B1, pk1 ? vfc1 : vfc0, r1);
      r1 = ff(A1.yx, pk1 ? vfb1 : vfb0, r1);
      r1 = ff(B1.yx, vqw, r1);
      a[kp] = r1;
    }
  }
}

// 3 x [ring CNOT (free GF(2) relabeling) + 8 RY]; same verified constants.
template<typename CPtr>
__device__ __forceinline__ void layers32(f2* a, CPtr L, int lam) {
  ry32<0xC0,0x7F>(a, L[0],  lam);
  ry32<0x60,0xC0>(a, L[1],  lam);
  ry32<0x30,0xE0>(a, L[2],  lam);
  ry32<0x18,0xF0>(a, L[3],  lam);
  ry32<0x0C,0xF8>(a, L[4],  lam);
  ry32<0x06,0xFC>(a, L[5],  lam);
  ry32<0x03,0xFE>(a, L[6],  lam);
  ry32<0xC1,0xFF>(a, L[7],  lam);
  ry32<0xA0,0xD5>(a, L[8],  lam);
  ry32<0x50,0xBF>(a, L[9],  lam);
  ry32<0x28,0x5F>(a, L[10], lam);
  ry32<0x14,0xAF>(a, L[11], lam);
  ry32<0x0A,0x57>(a, L[12], lam);
  ry32<0x05,0xAB>(a, L[13], lam);
  ry32<0xC2,0x55>(a, L[14], lam);
  ry32<0x61,0xAA>(a, L[15], lam);
  ry32<0xF0,0x4C>(a, L[16], lam);
  ry32<0x78,0x6A>(a, L[17], lam);
  ry32<0x3C,0x35>(a, L[18], lam);
  ry32<0x1E,0x9A>(a, L[19], lam);
  ry32<0x0F,0xCD>(a, L[20], lam);
  ry32<0xC7,0x66>(a, L[21], lam);
  ry32<0xA3,0x33>(a, L[22], lam);
  ry32<0x91,0x99>(a, L[23], lam);
}

// initial fused RX*RY on all 8 wires (variational halves; F0 = I)
template<typename FPtr>
__device__ __forceinline__ void initial32(f2* a, FPtr F, int lam) {
  su2_32<0x80,0x80>(a, F[0], lam);
  su2_32<0x40,0x40>(a, F[1], lam);
  su2_32<0x20,0x20>(a, F[2], lam);
  su2_32<0x10,0x10>(a, F[3], lam);
  su2_32<0x08,0x08>(a, F[4], lam);
  su2_32<0x04,0x04>(a, F[5], lam);
  su2_32<0x02,0x02>(a, F[6], lam);
  su2_32<0x01,0x01>(a, F[7], lam);
}

// Encoding half from |0..0>: product state, zero exchanges.
__device__ __forceinline__ void pinit32(f2* a, const float4* F, int lam) {
  f2 c = {1.f, 0.f};
#pragma unroll
  for (int i = 0; i < 3; ++i)
    c = cmul(c, uget(F[7 - i], ((lam >> i) & 1) != 0));
  f2 wlo[4], whi[8];
#pragma unroll
  for (int t = 0; t < 4; ++t)
    wlo[t] = cmul(uget(F[4], (t & 1) != 0), uget(F[3], ((t >> 1) & 1) != 0));
#pragma unroll
  for (int t = 0; t < 8; ++t)
    whi[t] = cmul(cmul(uget(F[2], (t & 1) != 0), uget(F[1], ((t >> 1) & 1) != 0)),
                  uget(F[0], ((t >> 2) & 1) != 0));
#pragma unroll
  for (int k = 0; k < 32; ++k)
    a[k] = cmul(cmul(c, wlo[k & 3]), whi[k >> 2]);
}

__device__ __forceinline__ uint32_t packh(f2 v) {
  h2v h = __builtin_amdgcn_cvt_pkrtz(v.x, v.y);
  return __builtin_bit_cast(uint32_t, h);
}
__device__ __forceinline__ f2 unpackh(uint32_t u) {
  h2v h = __builtin_bit_cast(h2v, u);
  f2 r; r.x = (float)h[0]; r.y = (float)h[1]; return r;
}

// F3 target address for the snapshot relabel reset (value at slot p -> F3*p)
__device__ __forceinline__ int snap_tgt_lane(int lam) {
  int tgt = 0;
  if (lam & 1) tgt ^= 0x2B;
  if (lam & 2) tgt ^= 0x56;
  if (lam & 4) tgt ^= 0xAC;
  return tgt;
}
__device__ __forceinline__ int snap_rck(int k) {
  return ((k & 1) ? 0xD9 : 0) ^ ((k & 2) ? 0x33 : 0) ^ ((k & 4) ? 0x66 : 0)
       ^ ((k & 8) ? 0xCC : 0) ^ ((k & 16) ? 0x19 : 0);
}

// split-path snapshot: per-circuit 256 words, word = (q&7)*32 + (q>>3)
__device__ __forceinline__ void snap_write_g(const f2* a, uint32_t* sn, int lam) {
  const int tgt = snap_tgt_lane(lam);
#pragma unroll
  for (int k = 0; k < 32; ++k) {
    const int qq = tgt ^ snap_rck(k);
    sn[(qq & 7) * 32 + (qq >> 3)] = packh(a[k]);
  }
}

// mono-path snapshot (stride 36, as in the proven 77us kernel)
__device__ __forceinline__ void snap_write_m(const f2* a, uint32_t* sn, int lam) {
  const int tgt = snap_tgt_lane(lam);
#pragma unroll
  for (int k = 0; k < 32; ++k) {
    const int qq = tgt ^ snap_rck(k);
    sn[(qq & 7) * 36 + (qq >> 3)] = packh(a[k]);
  }
}
__device__ __forceinline__ void snap_read_m(f2* a, const uint32_t* sn, int lam) {
  const uint4* p = (const uint4*)(sn + lam * 36);
#pragma unroll
  for (int t = 0; t < 8; ++t) {
    const uint4 w = p[t];
    a[4*t+0] = unpackh(w.x); a[4*t+1] = unpackh(w.y);
    a[4*t+2] = unpackh(w.z); a[4*t+3] = unpackh(w.w);
  }
}

// <Z...>: Z0 -> SM 0x4C; Zall -> SM 0x88 (F3 rows; unchanged constants)
template<int SM>
__device__ __forceinline__ float expect32(const f2* a, int lam) {
  constexpr int SL = SM & 7, SR = SM >> 3;
  float s0 = 0.f, s1 = 0.f;
#pragma unroll
  for (int k = 0; k < 32; ++k) {
    const float p = a[k].x * a[k].x + a[k].y * a[k].y;
    if ((__builtin_popcount(k & SR) & 1) != 0) s1 += p; else s0 += p;
  }
  const float d = s0 - s1;
  float v;
  if constexpr (SL != 0) v = (__popc(lam & SL) & 1) ? -d : d;
  else                   v = d;
  v += xch1<1>(v); v += xch1<2>(v); v += xch1<4>(v);
  return v;
}

// fill one wave's 8 enc coef tables (wave-private; lgkmcnt orders LDS ops)
__device__ __forceinline__ void fill_etab(float (*et)[84], const float* __restrict__ x,
                                          int bbase, int s, int lane) {
  for (int t = lane; t < 320; t += 64) {
    const int cc = t / 40, idx = t - cc * 40;
    const float ang = x[((size_t)(bbase + cc) * 64 + s) * 40 + idx];
    float sn, cn; __sincosf(ang * 0.5f, &sn, &cn);
    if (idx < 16) {
      const int wire = idx >> 1, isy = idx & 1;
      et[cc][wire * 4 + isy * 2 + 0] = cn;
      et[cc][wire * 4 + isy * 2 + 1] = sn;
    } else {
      et[cc][32 + (idx - 16) * 2 + 0] = cn;
      et[cc][32 + (idx - 16) * 2 + 1] = sn;
    }
  }
  {  // fold (cx,sx,cy,sy) -> (a,b,c2,d): 8 circuits x 8 wires = 64 lanes
    const int cc = lane >> 3, wire = lane & 7;
    float4* qt = (float4*)et[cc];
    const float4 f = qt[wire];
    qt[wire] = make_float4(f.z * f.x, f.w * f.y, f.w * f.x, f.z * f.y);
  }
}

// per-(s,half) variational coefficient tables: 80 floats = 8*float4 + 24*float2
__global__ __launch_bounds__(256) void prep_var(
    const float* __restrict__ pQ, const float* __restrict__ pK,
    const float* __restrict__ pV, float* __restrict__ vtab)
{
  const int t = blockIdx.x * 256 + threadIdx.x;
  if (t >= SEQd * 3 * 32) return;
  const int slot = t & 31;
  const int sh = t >> 5;
  const int h = sh % 3, sp = sh / 3;
  const float* w = ((h == 0) ? pQ : (h == 1) ? pK : pV) + sp * DF;
  float* o = vtab + sh * 80;
  if (slot < 8) {
    float cx, sx, cy, sy;
    __sincosf(w[2 * slot]     * 0.5f, &sx, &cx);
    __sincosf(w[2 * slot + 1] * 0.5f, &sy, &cy);
    ((float4*)o)[slot] = make_float4(cy * cx, sy * sx, sy * cx, cy * sx);
  } else {
    float sn, cn;
    __sincosf(w[16 + (slot - 8)] * 0.5f, &sn, &cn);
    ((float2*)(o + 32))[slot - 8] = make_float2(cn, sn);
  }
}

// === Kernel A: encoding halves -> fp16 snapshot in global (coalesced) ======
__global__ __launch_bounds__(256, 3) void qsal_enc(
    const float* __restrict__ x, uint32_t* __restrict__ snapg)
{
  __shared__ __align__(16) float etab[4][8][84];
  __shared__ __align__(16) uint32_t snap[4][8][264];
  const int tid = threadIdx.x;
  const int wid = tid >> 6, lane = tid & 63;
  const int lam = lane & 7, cig = lane >> 3;
  const int cgrp = blockIdx.x * 4 + wid;
  const int s = cgrp & 63;
  const int bbase = (cgrp >> 6) << 3;

  fill_etab(etab[wid], x, bbase, s, lane);

  f2 st[32];
  pinit32(st, (const float4*)etab[wid][cig], lam);
  layers32(st, (const f2*)(etab[wid][cig] + 32), lam);
  snap_write_g(st, snap[wid][cig], lam);

  // LDS -> global, coalesced: each circuit's 256 words are q-linear
  uint32_t* gb = snapg + ((size_t)cgrp * 8 + cig) * 256;
#pragma unroll
  for (int r = 0; r < 8; ++r) {
    const int u4 = lam + 8 * r;                       // uint4 idx 0..63
    const uint4 v = *(const uint4*)&snap[wid][cig][u4 * 4];
    ((uint4*)gb)[u4] = v;
  }
}

// === Kernel B: one variational half per wave (3 waves/block, no barriers) ==
// min-waves=3 -> VGPR cap ~170: keeps the 64-reg state resident (R9: 60 VGPR
// -> scratch spill -> 59us; the whole point of this bound).
__global__ __launch_bounds__(192, 3) void qsal_var(
    const uint32_t* __restrict__ snapg, const float* __restrict__ vtab,
    float* __restrict__ Qo, float* __restrict__ Ko, float* __restrict__ Vo)
{
  __shared__ __align__(16) float ltab[3][80];
  const int tid = threadIdx.x;
  const int h = tid / 64, lane = tid & 63;           // h = wave id = half
  const int lam = lane & 7, cig = lane >> 3;
  const int cgrp = blockIdx.x;
  const int s = cgrp & 63;
  const int bbase = (cgrp >> 6) << 3;

  if (lane < 20)
    ((float4*)ltab[h])[lane] = ((const float4*)(vtab + s * 240 + h * 80))[lane];

  f2 st[32];
  const uint4* sp = (const uint4*)(snapg + (((size_t)cgrp * 8 + cig) * 256 + lam * 32));
#pragma unroll
  for (int t = 0; t < 8; ++t) {
    const uint4 w = sp[t];
    st[4*t+0] = unpackh(w.x); st[4*t+1] = unpackh(w.y);
    st[4*t+2] = unpackh(w.z); st[4*t+3] = unpackh(w.w);
  }
  initial32(st, (const float4*)ltab[h], lam);
  layers32(st, (const f2*)(ltab[h] + 32), lam);
  const float e = (h == 2) ? expect32<0x88>(st, lam) : expect32<0x4C>(st, lam);
  if (lam == 0) {
    float* op = (h == 0) ? Qo : (h == 1) ? Ko : Vo;
    op[(bbase + cig) * 64 + s] = e;
  }
}

// === Fallback: the proven 77us monolithic kernel (ws too small for split) ==
__global__ __launch_bounds__(256, 3) void qsal_mono(
    const float* __restrict__ x, const float* __restrict__ vtab,
    float* __restrict__ Qo, float* __restrict__ Ko, float* __restrict__ Vo)
{
  __shared__ __align__(16) float etab[32][84];
  __shared__ __align__(16) uint32_t snap[32][296];
  __shared__ __align__(16) float vtabs[240];
  const int tid = threadIdx.x;
  const int wid = tid >> 6, lane = tid & 63;
  const int lam = lane & 7;
  const int cig = (wid << 3) | (lane >> 3);
  const int s = blockIdx.x & 63;
  const int bbase = (blockIdx.x >> 6) << 5;

  for (int t = tid; t < 1280; t += 256) {
    const int cc = t / 40, idx = t - cc * 40;
    const float ang = x[((size_t)(bbase + cc) * 64 + s) * 40 + idx];
    float sn, cn; __sincosf(ang * 0.5f, &sn, &cn);
    if (idx < 16) {
      const int wire = idx >> 1, isy = idx & 1;
      etab[cc][wire * 4 + isy * 2 + 0] = cn;
      etab[cc][wire * 4 + isy * 2 + 1] = sn;
    } else {
      etab[cc][32 + (idx - 16) * 2 + 0] = cn;
      etab[cc][32 + (idx - 16) * 2 + 1] = sn;
    }
  }
  if (tid < 60) ((float4*)vtabs)[tid] = ((const float4*)(vtab + s * 240))[tid];
  __syncthreads();
  {
    const int cc = tid >> 3, wire = tid & 7;
    float4* qt = (float4*)etab[cc];
    const float4 f = qt[wire];
    qt[wire] = make_float4(f.z * f.x, f.w * f.y, f.w * f.x, f.z * f.y);
  }
  __syncthreads();

  f2 st[32];
#pragma unroll 1
  for (int ph = 0; ph < 4; ++ph) {
    const f2* L;
    if (ph == 0) {
      pinit32(st, (const float4*)etab[cig], lam);
      L = (const f2*)(etab[cig] + 32);
    } else {
      snap_read_m(st, snap[cig], lam);
      const float* th = vtabs + (ph - 1) * 80;
      initial32(st, (const float4*)th, lam);
      L = (const f2*)(th + 32);
    }
    layers32(st, L, lam);
    if (ph == 0) {
      snap_write_m(st, snap[cig], lam);
    } else {
      const float e = (ph == 3) ? expect32<0x88>(st, lam) : expect32<0x4C>(st, lam);
      if (lam == 0) {
        float* op = (ph == 1) ? Qo : (ph == 2) ? Ko : Vo;
        op[(bbase + cig) * 64 + s] = e;
      }
    }
    __syncthreads();
  }
}

__global__ __launch_bounds__(256) void qsal_attn(
    const float* __restrict__ x,
    const float* __restrict__ Qv,
    const float* __restrict__ Kv,
    const float* __restrict__ Vv,
    float* __restrict__ out)
{
  const int tid  = threadIdx.x;
  const int wid  = tid >> 6;
  const int lane = tid & 63;                 // m
  const int bi   = blockIdx.x * 4 + wid;     // b*64 + i
  const int b    = bi >> 6;

  const float q = Qv[bi];
  const float k = Kv[b * 64 + lane];
  const float v = Vv[b * 64 + lane];
  const float d = q - k;
  float e  = __expf(-d * d);
  float ev = e * v;
#pragma unroll
  for (int m = 1; m < 64; m <<= 1) {
    e  += __shfl_xor(e,  m, 64);
    ev += __shfl_xor(ev, m, 64);
  }
  const float att = ev / e;

  const size_t row = (size_t)bi * DF;
  if (lane < DF) out[row + lane] = x[row + lane] + att;
}

extern "C" void kernel_launch(void* const* d_in, const int* in_sizes, int n_in,
                              void* d_out, int out_size, void* d_ws, size_t ws_size,
                              hipStream_t stream) {
  const float* x  = (const float*)d_in[0];
  const float* pQ = (const float*)d_in[1];
  const float* pK = (const float*)d_in[2];
  const float* pV = (const float*)d_in[3];
  float* out = (float*)d_out;

  const int NC = BATCHd * SEQd;                  // 16384 circuits
  float* Qv   = (float*)d_ws;                    // [16384]
  float* Kv   = Qv + NC;
  float* Vv   = Kv + NC;
  float* vtab = Vv + NC;                         // [64*3*80] = 15360
  uint32_t* snapg = (uint32_t*)(vtab + SEQd * 3 * 80);   // [16384*256] u32 = 16 MB

  const size_t need = (size_t)(3 * NC + SEQd * 3 * 80) * 4 + (size_t)NC * 256 * 4;

  prep_var<<<dim3(24), dim3(256), 0, stream>>>(pQ, pK, pV, vtab);
  if (ws_size >= need) {
    qsal_enc<<<dim3(512), dim3(256), 0, stream>>>(x, snapg);
    qsal_var<<<dim3(2048), dim3(192), 0, stream>>>(snapg, vtab, Qv, Kv, Vv);
  } else {
    qsal_mono<<<dim3(512), dim3(256), 0, stream>>>(x, vtab, Qv, Kv, Vv);
  }
  qsal_attn<<<dim3(NC / 4), dim3(256), 0, stream>>>(x, Qv, Kv, Vv, out);
}